// Round 7
// baseline (1022.166 us; speedup 1.0000x reference)
//
#include <hip/hip_runtime.h>
#include <hip/hip_bf16.h>

// FLASH/GAU block: B=4 N=4096 DIM=1024 QK=128 G=256, all GEMMs in TN form
// (A: MxK row-major, B: NxK row-major, K contiguous).
// Big GEMMs (mode 0 hid, mode 6 final): REGISTER-STREAMING GEMM — no LDS, no
// barriers. 4 waves (2Mx2N), per-wave 64x64 output, BK=32, both operands
// loaded global->VGPR (16-row x 64B coalesced), register double-buffered,
// 3 blocks/CU. Rationale: six LDS-staged schedule variants all pinned at
// ~30% MfmaUtil because required LDS BW (~127 B/cyc/CU) exceeds the pipe
// (~85-112); streaming moves operand duplication to L1/L2 (~53 B/cyc L2
// before L1 filtering), which is feasible. XCD remap keeps each XCD's
// A-working-set = 4 MB (L2-resident).
// Small/medium GEMMs (modes 1,2,3,4): previous 128x128 m97-structure kernel.

typedef __attribute__((ext_vector_type(8))) short short8;
typedef __attribute__((ext_vector_type(4))) float f32x4;

#define BM 128
#define BN 128
#define BK 32

struct Aux {
  const float* b1;              // bias vec (b_h / b_qk / b_out)
  const float* x;               // residual (mode6)
  const float* gamma;           // os_gamma (mode1)
  const float* beta;            // os_beta  (mode1)
  const float* biastab;         // rel-pos table (mode2)
  const unsigned short* a2;     // mode3 tail A: lin_q (16384x128)
  const unsigned short* bkv;    // mode3 tail B: linkvT (4x2048x128)
  const unsigned short* gate;   // mode3: bf16 gate
  unsigned short* o16a;
  unsigned short* o16b;
  unsigned short* o16c;
  unsigned short* o16d;
  float* o32;
};

__device__ __forceinline__ float bf2f(unsigned short u) {
  union { float f; unsigned int i; } w; w.i = ((unsigned int)u) << 16; return w.f;
}
__device__ __forceinline__ unsigned short f2bf(float f) {
  union { float f; unsigned int i; } w; w.f = f;
  unsigned int x = w.i;
  return (unsigned short)((x + 0x7FFFu + ((x >> 16) & 1u)) >> 16);
}
__device__ __forceinline__ float silu_f(float z) { return z / (1.0f + __expf(-z)); }

// async global->LDS, 16B per lane; lptr must be the wave-uniform base
__device__ __forceinline__ void async_cp16(const void* g, void* l) {
  __builtin_amdgcn_global_load_lds(
      (const __attribute__((address_space(1))) void*)g,
      (__attribute__((address_space(3))) void*)l, 16, 0, 0);
}

__device__ __forceinline__ float block_sum(float v) {
  #pragma unroll
  for (int o = 32; o > 0; o >>= 1) v += __shfl_down(v, o, 64);
  __shared__ float sh[4];
  __syncthreads();
  if ((threadIdx.x & 63) == 0) sh[threadIdx.x >> 6] = v;
  __syncthreads();
  return sh[0] + sh[1] + sh[2] + sh[3];
}

// LayerNorm over DIM=1024, one block per row, output bf16.
__global__ __launch_bounds__(256) void ln_k(const float* __restrict__ x,
                                            const float* __restrict__ g,
                                            const float* __restrict__ b,
                                            unsigned short* __restrict__ out) {
  const int row = blockIdx.x;
  const int tid = threadIdx.x;
  const float4 xv = ((const float4*)(x + (size_t)row * 1024))[tid];
  float s = xv.x + xv.y + xv.z + xv.w;
  s = block_sum(s);
  const float mu = s * (1.0f / 1024.0f);
  const float d0 = xv.x - mu, d1 = xv.y - mu, d2 = xv.z - mu, d3 = xv.w - mu;
  float q = d0 * d0 + d1 * d1 + d2 * d2 + d3 * d3;
  q = block_sum(q);
  const float rstd = rsqrtf(q * (1.0f / 1024.0f) + 1e-5f);
  const float4 gv = ((const float4*)g)[tid];
  const float4 bv = ((const float4*)b)[tid];
  unsigned short* o = out + (size_t)row * 1024 + tid * 4;
  o[0] = f2bf(d0 * rstd * gv.x + bv.x);
  o[1] = f2bf(d1 * rstd * gv.y + bv.y);
  o[2] = f2bf(d2 * rstd * gv.z + bv.z);
  o[3] = f2bf(d3 * rstd * gv.w + bv.w);
}

// transpose-cast: in[K][N] fp32 -> out[N][K] bf16, 64x64 LDS tiles
__global__ __launch_bounds__(256) void tc_k(const float* __restrict__ in,
                                            unsigned short* __restrict__ out,
                                            int K, int N) {
  __shared__ unsigned short L[64][65];
  const int t = threadIdx.x;
  const int k0 = blockIdx.y * 64, n0 = blockIdx.x * 64;
  const int r = t >> 4, c4 = (t & 15) * 4;
  #pragma unroll
  for (int rr = 0; rr < 4; ++rr) {
    const int kk = rr * 16 + r;
    const float4 f = ((const float4*)(in + (size_t)(k0 + kk) * N + n0))[t & 15];
    L[kk][c4 + 0] = f2bf(f.x); L[kk][c4 + 1] = f2bf(f.y);
    L[kk][c4 + 2] = f2bf(f.z); L[kk][c4 + 3] = f2bf(f.w);
  }
  __syncthreads();
  #pragma unroll
  for (int rr = 0; rr < 4; ++rr) {
    const int nn = rr * 16 + r;
    ushort4 u;
    u.x = L[c4 + 0][nn]; u.y = L[c4 + 1][nn];
    u.z = L[c4 + 2][nn]; u.w = L[c4 + 3][nn];
    ((ushort4*)(out + (size_t)(n0 + nn) * K + k0))[t & 15] = u;
  }
}

// rel-pos bias table: tab[d + 255] for d = j - i in [-255, 255]
__global__ void bias_k(const float* __restrict__ rel, float* __restrict__ tab) {
  int idx = blockIdx.x * 256 + threadIdx.x;
  if (idx >= 511) return;
  int d = idx - 255;       // j - i
  int n = -d;              // i - j
  int ret = (n < 0) ? 16 : 0;
  int a = (n < 0) ? -n : n;
  int bucket;
  if (a < 8) {
    bucket = ret + a;
  } else {
    float t = __logf((float)a * 0.125f) / 2.7725887298583984f * 8.0f;
    int vl = 8 + (int)t;
    if (vl > 15) vl = 15;
    bucket = ret + vl;
  }
  tab[idx] = rel[bucket] * 11.313708498984761f;  // * sqrt(QK)
}

// reduce 4 split-K partials of pkvT[b][s][e][d], scale 1/N, cast -> linkvT[b][e][d]
__global__ void kvred_k(const float* __restrict__ pkv, unsigned short* __restrict__ linkvT) {
  int i4 = blockIdx.x * 256 + threadIdx.x;   // < 262144 (float4 units)
  const int b = i4 >> 16, rem = i4 & 65535;
  const float4* p = (const float4*)(pkv + (size_t)b * 1048576) + rem;
  const float4 p0 = p[0], p1 = p[65536], p2 = p[131072], p3 = p[196608];
  ushort4 u;
  u.x = f2bf((p0.x + p1.x + p2.x + p3.x) * (1.0f / 4096.0f));
  u.y = f2bf((p0.y + p1.y + p2.y + p3.y) * (1.0f / 4096.0f));
  u.z = f2bf((p0.z + p1.z + p2.z + p3.z) * (1.0f / 4096.0f));
  u.w = f2bf((p0.w + p1.w + p2.w + p3.w) * (1.0f / 4096.0f));
  ((ushort4*)(linkvT + (size_t)b * 262144))[rem] = u;
}

// ---------------------------------------------------------------------------
// Register-streaming GEMM (no LDS, no barriers). C = A(MxK) @ B(NxK)^T, bf16.
// MODE 0: hid   M=16384 N=4096 K=1024 (kiters=32); epi silu(+b_h) -> vT | gate
// MODE 6: final M=16384 N=1024 K=2048 (kiters=64); epi +b_out +x -> fp32 out
//
// 256 threads = 4 waves (2Mx2N), per-wave 64x64 output: acc[4][4] f32x4.
// Per K-tile (BK=32) each wave loads 4 A-frags + 4 B-frags (short8 global
// loads; lane pattern = 16 rows x 64 B contiguous -> 16 full cache lines).
// Register double-buffer via x2 unroll; compiler manages vmcnt. Intra-CU
// operand duplication (A x2 waves, B x2 waves) is filtered by L1.
//
// XCD remap (dispatch index L, XCD = L%8 round-robin): each XCD owns a
// contiguous set of M-panels totaling 4 MB (L2-resident A), bx iterates
// inside so B-panels stay hot:
//   MODE 0 (gy=128, K=1024, panel 256KB): 16 panels/XCD:
//     p=L&7; s=L>>3; by=p*16+(s&15); bx=s>>4.
//   MODE 6 (gy=128, K=2048, panel 512KB): 8 panels/XCD x 2 sweeps:
//     p=L&7; s=L>>3; by=(p+8*(s>>6))*8+(s&7); bx=(s>>3)&7.
// ---------------------------------------------------------------------------
template<int MODE>
__global__ __launch_bounds__(256, 3) void gemmrs_k(
    const unsigned short* __restrict__ Ag,
    const unsigned short* __restrict__ Bg,
    int lda, int ldb, int kiters, Aux aux)
{
  const int tid  = threadIdx.x;
  const int lane = tid & 63;
  const int wave = tid >> 6;
  const int quad = lane >> 4;
  const int l16  = lane & 15;
  const int wm   = (wave >> 1) * 64;
  const int wn   = (wave & 1) * 64;

  const int L = blockIdx.x + gridDim.x * blockIdx.y;
  const int p = L & 7;
  const int s = L >> 3;
  int by, bx;
  if constexpr (MODE == 6) { by = (p + 8 * (s >> 6)) * 8 + (s & 7); bx = (s >> 3) & 7; }
  else                     { by = p * 16 + (s & 15);                bx = s >> 4; }
  const int bm = by * 128;
  const int bn = bx * 128;

  // per-frag running pointers: lane reads row (frag base + l16), 16B at quad*16
  const unsigned lda2 = (unsigned)lda * 2u;
  const unsigned ldb2 = (unsigned)ldb * 2u;
  const char* pa[4];
  const char* pb[4];
  #pragma unroll
  for (int i = 0; i < 4; ++i)
    pa[i] = (const char*)Ag + (size_t)(unsigned)((bm + wm + i * 16 + l16) * lda2) + quad * 16;
  #pragma unroll
  for (int j = 0; j < 4; ++j)
    pb[j] = (const char*)Bg + (size_t)(unsigned)((bn + wn + j * 16 + l16) * ldb2) + quad * 16;

  const f32x4 zero = {0.f, 0.f, 0.f, 0.f};
  f32x4 acc[4][4];
  #pragma unroll
  for (int i = 0; i < 4; ++i)
    #pragma unroll
    for (int j = 0; j < 4; ++j) acc[i][j] = zero;

  short8 ca[4], cb[4], na[4], nb[4];

#define LOAD8(DA, DB)                                            \
  _Pragma("unroll")                                              \
  for (int i = 0; i < 4; ++i) {                                  \
    DA[i] = *(const short8*)pa[i];  pa[i] += 64;                 \
    DB[i] = *(const short8*)pb[i];  pb[i] += 64;                 \
  }
#define MFMA16(SA, SB)                                           \
  _Pragma("unroll")                                              \
  for (int i = 0; i < 4; ++i)                                    \
    _Pragma("unroll")                                            \
    for (int j = 0; j < 4; ++j)                                  \
      acc[i][j] = __builtin_amdgcn_mfma_f32_16x16x32_bf16(       \
          SA[i], SB[j], acc[i][j], 0, 0, 0);

  LOAD8(ca, cb);                       // tile 0
  for (int t = 0; t < kiters; t += 2) {  // kiters even (32 / 64)
    if (t + 1 < kiters) LOAD8(na, nb);   // tile t+1 in flight under MFMA(t)
    MFMA16(ca, cb);
    if (t + 2 < kiters) LOAD8(ca, cb);   // tile t+2 in flight under MFMA(t+1)
    MFMA16(na, nb);
  }
#undef LOAD8
#undef MFMA16

  // epilogue: D[row=quad*4+r][col=l16] per 16x16 tile
  #pragma unroll
  for (int i = 0; i < 4; ++i) {
    #pragma unroll
    for (int j = 0; j < 4; ++j) {
      const int row0 = bm + wm + i * 16 + quad * 4;
      const int col  = bn + wn + j * 16 + l16;
      if constexpr (MODE == 0) {
        const float bb = aux.b1[col];
        float s4[4];
        #pragma unroll
        for (int r = 0; r < 4; ++r) s4[r] = silu_f(acc[i][j][r] + bb);
        if (col < 2048) {          // vT[b][e][t] (uniform per block: 128 | 2048)
          const int b = row0 >> 12, tt = row0 & 4095;
          ushort4 u; u.x = f2bf(s4[0]); u.y = f2bf(s4[1]); u.z = f2bf(s4[2]); u.w = f2bf(s4[3]);
          *(ushort4*)(aux.o16a + (size_t)b * 8388608 + (size_t)col * 4096 + tt) = u;
        } else {                   // gate row-major
          #pragma unroll
          for (int r = 0; r < 4; ++r)
            aux.o16b[(size_t)(row0 + r) * 2048 + (col - 2048)] = f2bf(s4[r]);
        }
      } else {  // MODE == 6
        #pragma unroll
        for (int r = 0; r < 4; ++r) {
          const size_t idx = (size_t)(row0 + r) * 1024 + col;
          aux.o32[idx] = acc[i][j][r] + aux.b1[col] + aux.x[idx];
        }
      }
    }
  }
}

// ---------------------------------------------------------------------------
// Previous 128x128 kernel, kept for modes 1,2,3,4.
// MODE 1: qk    M=16384 N=128  K=1024; epi silu(+b_qk): qq/lq/qkk + linkT
// MODE 2: sim   per-group M=N=256 K=128; epi /G +bias, relu^2 -> attn
// MODE 3: quad+lin per-group M=256 N=2048 K=256(attn@vT)+128(lq@linkvT); epi *gate
// MODE 4: lin_kv split-K x4 per batch M=128(d) N=2048(e) K=1024; epi fp32 pkvT
// ---------------------------------------------------------------------------
template<int MODE>
__global__ __launch_bounds__(256, 2) void gemm_k(
    const unsigned short* __restrict__ Ag,
    const unsigned short* __restrict__ Bg,
    int lda, int ldb, int kiters, Aux aux)
{
  __shared__ unsigned short As[BM * BK];
  __shared__ unsigned short Bs[BN * BK];

  const int tid  = threadIdx.x;
  const int lane = tid & 63;
  const int wave = tid >> 6;
  const int quad = lane >> 4;
  const int l16  = lane & 15;
  const int wm   = (wave >> 1) * 64;
  const int wn   = (wave & 1) * 64;
  const int bz   = blockIdx.z;
  const int bm   = blockIdx.y * BM;
  const int bn   = blockIdx.x * BN;

  const unsigned short* A = Ag;
  const unsigned short* B = Bg;
  if constexpr (MODE == 2) { A += (size_t)bz * 32768;  B += (size_t)bz * 32768; }
  if constexpr (MODE == 3) { A += (size_t)bz * 65536;                       // attn group
                             B += (size_t)(bz >> 4) * 8388608 + (size_t)(bz & 15) * 256; } // vT + g*256
  if constexpr (MODE == 4) { const int b = bz >> 2, s = bz & 3;
                             A += (size_t)b * 524288 + (size_t)s * 1024;    // linkT cols s*1024..
                             B += (size_t)b * 8388608 + (size_t)s * 1024; } // vT cols s*1024..

  const unsigned short* A2 = nullptr;
  const unsigned short* B2 = nullptr;
  if constexpr (MODE == 3) {
    A2 = aux.a2 + (size_t)bz * 32768;            // lq group (256x128)
    B2 = aux.bkv + (size_t)(bz >> 4) * 262144;   // linkvT batch (2048x128)
  }

  const int srow = wave * 32 + (lane >> 2);  // staging row (+16 for 2nd issue)
  const int scol = (lane & 3) * 8;           // staging col (8 bf16 = 16B)
  unsigned short* lA = As + wave * 1024;     // wave-uniform LDS bases
  unsigned short* lB = Bs + wave * 1024;

  const f32x4 zero = {0.f, 0.f, 0.f, 0.f};
  f32x4 acc[4][4];
  #pragma unroll
  for (int i = 0; i < 4; ++i)
    #pragma unroll
    for (int j = 0; j < 4; ++j) acc[i][j] = zero;

  for (int kt = 0; kt < kiters; ++kt) {
    const unsigned short* pa = A;
    const unsigned short* pb = B;
    int la = lda, lb = ldb, kk = kt * BK;
    if constexpr (MODE == 3) {
      if (kt >= 8) { pa = A2; pb = B2; la = 128; lb = 128; kk -= 256; }
    }

    __syncthreads();  // prior iteration's LDS reads complete
    async_cp16(pa + (size_t)(bm + srow) * la + kk + scol, lA);
    async_cp16(pa + (size_t)(bm + srow + 16) * la + kk + scol, lA + 512);
    async_cp16(pb + (size_t)(bn + srow) * lb + kk + scol, lB);
    async_cp16(pb + (size_t)(bn + srow + 16) * lb + kk + scol, lB + 512);
    __syncthreads();  // drains vmcnt (compiler) -> staged data visible

    short8 af[4], bfv[4];
    #pragma unroll
    for (int i = 0; i < 4; ++i)
      af[i] = *reinterpret_cast<const short8*>(As + (wm + i * 16 + l16) * BK + quad * 8);
    #pragma unroll
    for (int j = 0; j < 4; ++j)
      bfv[j] = *reinterpret_cast<const short8*>(Bs + (wn + j * 16 + l16) * BK + quad * 8);

    #pragma unroll
    for (int i = 0; i < 4; ++i)
      #pragma unroll
      for (int j = 0; j < 4; ++j)
        acc[i][j] = __builtin_amdgcn_mfma_f32_16x16x32_bf16(af[i], bfv[j], acc[i][j], 0, 0, 0);
  }

  // epilogue: D[row=quad*4+r][col=l16] per 16x16 tile
  #pragma unroll
  for (int i = 0; i < 4; ++i) {
    #pragma unroll
    for (int j = 0; j < 4; ++j) {
      const int row0 = bm + wm + i * 16 + quad * 4;
      const int col  = bn + wn + j * 16 + l16;
      if constexpr (MODE == 1) {
        const float bb = aux.b1[col];
        float s[4];
        #pragma unroll
        for (int r = 0; r < 4; ++r) s[r] = silu_f(acc[i][j][r] + bb);
        #pragma unroll
        for (int r = 0; r < 4; ++r) {
          const size_t idx = (size_t)(row0 + r) * 128 + col;
          aux.o16a[idx] = f2bf(s[r] * aux.gamma[col]       + aux.beta[col]);        // quad_q
          aux.o16b[idx] = f2bf(s[r] * aux.gamma[128 + col] + aux.beta[128 + col]);  // lin_q
          aux.o16c[idx] = f2bf(s[r] * aux.gamma[256 + col] + aux.beta[256 + col]);  // quad_k
        }
        const int b = row0 >> 12, t = row0 & 4095;                                  // lin_k^T
        const float g4 = aux.gamma[384 + col], b4 = aux.beta[384 + col];
        ushort4 u;
        u.x = f2bf(s[0] * g4 + b4); u.y = f2bf(s[1] * g4 + b4);
        u.z = f2bf(s[2] * g4 + b4); u.w = f2bf(s[3] * g4 + b4);
        *(ushort4*)(aux.o16d + (size_t)b * 524288 + (size_t)col * 4096 + t) = u;
      } else if constexpr (MODE == 2) {
        #pragma unroll
        for (int r = 0; r < 4; ++r) {
          float s = acc[i][j][r] * (1.0f / 256.0f) + aux.biastab[col - (row0 + r) + 255];
          s = fmaxf(s, 0.0f);
          aux.o16a[(size_t)bz * 65536 + (size_t)(row0 + r) * 256 + col] = f2bf(s * s);
        }
      } else if constexpr (MODE == 3) {
        #pragma unroll
        for (int r = 0; r < 4; ++r) {
          const size_t idx = ((size_t)bz * 256 + row0 + r) * 2048 + col;
          aux.o16a[idx] = f2bf(acc[i][j][r] * bf2f(aux.gate[idx]));
        }
      } else if constexpr (MODE == 4) {
        float4 u; u.x = acc[i][j][0]; u.y = acc[i][j][1]; u.z = acc[i][j][2]; u.w = acc[i][j][3];
        *(float4*)(aux.o32 + (size_t)bz * 262144 + (size_t)col * 128 + row0) = u;
      }
    }
  }
}

extern "C" void kernel_launch(void* const* d_in, const int* in_sizes, int n_in,
                              void* d_out, int out_size, void* d_ws, size_t ws_size,
                              hipStream_t stream) {
  (void)in_sizes; (void)n_in; (void)out_size; (void)ws_size;
  const float* x     = (const float*)d_in[0];
  const float* ln_g  = (const float*)d_in[1];
  const float* ln_b  = (const float*)d_in[2];
  const float* W_h   = (const float*)d_in[3];
  const float* b_h   = (const float*)d_in[4];
  const float* W_qk  = (const float*)d_in[5];
  const float* b_qk  = (const float*)d_in[6];
  const float* osg   = (const float*)d_in[7];
  const float* osb   = (const float*)d_in[8];
  const float* rel   = (const float*)d_in[9];
  const float* W_out = (const float*)d_in[10];
  const float* b_out = (const float*)d_in[11];
  float* out = (float*)d_out;

  char* w = (char*)d_ws;
  size_t off = 0;
  auto alloc = [&](size_t bytes) { char* p = w + off; off += (bytes + 255) & ~(size_t)255; return p; };

  // ---- arena R (all dead before mode 3 writes `gated`, which aliases R) ----
  unsigned short* normed = (unsigned short*)alloc(16384ull * 1024 * 2);   // 32M, dead after mode1
  unsigned short* whT    = (unsigned short*)alloc(4096ull * 1024 * 2);    //  8M, dead after mode0
  unsigned short* qq     = (unsigned short*)alloc(16384ull * 128 * 2);    //  4M, dead after mode2
  unsigned short* qkk    = (unsigned short*)alloc(16384ull * 128 * 2);    //  4M, dead after mode2
  unsigned short* linkT  = (unsigned short*)alloc(4ull * 128 * 4096 * 2); //  4M, dead after mode4
  float*          pkvT   = (float*)alloc(16ull * 2048 * 128 * 4);         // 16M, dead after kvred
  unsigned short* wqkT   = (unsigned short*)alloc(128ull * 1024 * 2);     // 256K, dead after mode1
  // ---- live-through buffers ----
  unsigned short* woutT  = (unsigned short*)alloc(1024ull * 2048 * 2);
  unsigned short* vT     = (unsigned short*)alloc(4ull * 2048 * 4096 * 2); // 64M
  unsigned short* gate   = (unsigned short*)alloc(16384ull * 2048 * 2);    // 64M
  unsigned short* lq     = (unsigned short*)alloc(16384ull * 128 * 2);
  unsigned short* attn   = (unsigned short*)alloc(64ull * 256 * 256 * 2);  //  8M
  unsigned short* linkvT = (unsigned short*)alloc(4ull * 2048 * 128 * 2);
  float*          btab   = (float*)alloc(511 * 4);
  unsigned short* gated  = (unsigned short*)w;  // alias arena R (64M needed, ~68M there)

  tc_k<<<dim3(64, 16), 256, 0, stream>>>(W_h,   whT,   1024, 4096);
  tc_k<<<dim3(2, 16),  256, 0, stream>>>(W_qk,  wqkT,  1024, 128);
  tc_k<<<dim3(16, 32), 256, 0, stream>>>(W_out, woutT, 2048, 1024);
  bias_k<<<2, 256, 0, stream>>>(rel, btab);
  ln_k<<<16384, 256, 0, stream>>>(x, ln_g, ln_b, normed);

  Aux a0{}; a0.b1 = b_h; a0.o16a = vT; a0.o16b = gate;
  gemmrs_k<0><<<dim3(32, 128), 256, 0, stream>>>(normed, whT, 1024, 1024, 32, a0);

  Aux a1{}; a1.b1 = b_qk; a1.gamma = osg; a1.beta = osb;
  a1.o16a = qq; a1.o16b = lq; a1.o16c = qkk; a1.o16d = linkT;
  gemm_k<1><<<dim3(1, 128, 1), 256, 0, stream>>>(normed, wqkT, 1024, 1024, 32, a1);

  Aux a2x{}; a2x.biastab = btab; a2x.o16a = attn;
  gemm_k<2><<<dim3(2, 2, 64), 256, 0, stream>>>(qq, qkk, 128, 128, 4, a2x);

  Aux a4{}; a4.o32 = pkvT;
  gemm_k<4><<<dim3(16, 1, 16), 256, 0, stream>>>(linkT, vT, 4096, 4096, 8, a4);

  kvred_k<<<1024, 256, 0, stream>>>(pkvT, linkvT);

  Aux a3{}; a3.a2 = lq; a3.bkv = linkvT; a3.gate = gate; a3.o16a = gated;
  gemm_k<3><<<dim3(16, 2, 64), 256, 0, stream>>>(attn, vT, 256, 4096, 12, a3);

  Aux a6{}; a6.b1 = b_out; a6.x = x; a6.o32 = out;
  gemmrs_k<6><<<dim3(8, 128), 256, 0, stream>>>(gated, woutT, 2048, 2048, 64, a6);
}

// Round 8
// 608.870 us; speedup vs baseline: 1.6788x; 1.6788x over previous
//
#include <hip/hip_runtime.h>
#include <hip/hip_bf16.h>

// FLASH/GAU block: B=4 N=4096 DIM=1024 QK=128 G=256, all GEMMs in TN form
// (A: MxK row-major, B: NxK row-major, K contiguous).
// Big GEMMs (modes 0, 3, 6): 256x256 tile, BK=32, 8 waves, 4-slot pipelined
// LDS (128 KiB), XOR-swizzled LDS reads, counted vmcnt gates, one-tile-ahead
// register prefetch, XCD/L2 block remap (modes 0/6). Mode 3 uses a per-tile
// source switch (attn@vT for t<8, lq@linkvT for t>=8) in the same schedule.
// Modes 1,2,4: 128x128 m97-structure kernel. prep_k fuses the 3 weight
// transposes + bias table into one launch (9 dispatches total).

typedef __attribute__((ext_vector_type(8))) short short8;
typedef __attribute__((ext_vector_type(4))) float f32x4;

#define BM 128
#define BN 128
#define BK 32

struct Aux {
  const float* b1;              // bias vec (b_h / b_qk / b_out)
  const float* x;               // residual (mode6)
  const float* gamma;           // os_gamma (mode1)
  const float* beta;            // os_beta  (mode1)
  const float* biastab;         // rel-pos table (mode2)
  const unsigned short* a2;     // mode3 tail A: lin_q (16384x128)
  const unsigned short* bkv;    // mode3 tail B: linkvT (4x2048x128)
  const unsigned short* gate;   // mode3: bf16 gate
  unsigned short* o16a;
  unsigned short* o16b;
  unsigned short* o16c;
  unsigned short* o16d;
  float* o32;
};

__device__ __forceinline__ float bf2f(unsigned short u) {
  union { float f; unsigned int i; } w; w.i = ((unsigned int)u) << 16; return w.f;
}
__device__ __forceinline__ unsigned short f2bf(float f) {
  union { float f; unsigned int i; } w; w.f = f;
  unsigned int x = w.i;
  return (unsigned short)((x + 0x7FFFu + ((x >> 16) & 1u)) >> 16);
}
__device__ __forceinline__ float silu_f(float z) { return z / (1.0f + __expf(-z)); }

// async global->LDS, 16B per lane; lptr must be the wave-uniform base
__device__ __forceinline__ void async_cp16(const void* g, void* l) {
  __builtin_amdgcn_global_load_lds(
      (const __attribute__((address_space(1))) void*)g,
      (__attribute__((address_space(3))) void*)l, 16, 0, 0);
}

__device__ __forceinline__ float block_sum(float v) {
  #pragma unroll
  for (int o = 32; o > 0; o >>= 1) v += __shfl_down(v, o, 64);
  __shared__ float sh[4];
  __syncthreads();
  if ((threadIdx.x & 63) == 0) sh[threadIdx.x >> 6] = v;
  __syncthreads();
  return sh[0] + sh[1] + sh[2] + sh[3];
}

// LayerNorm over DIM=1024, one block per row, output bf16.
__global__ __launch_bounds__(256) void ln_k(const float* __restrict__ x,
                                            const float* __restrict__ g,
                                            const float* __restrict__ b,
                                            unsigned short* __restrict__ out) {
  const int row = blockIdx.x;
  const int tid = threadIdx.x;
  const float4 xv = ((const float4*)(x + (size_t)row * 1024))[tid];
  float s = xv.x + xv.y + xv.z + xv.w;
  s = block_sum(s);
  const float mu = s * (1.0f / 1024.0f);
  const float d0 = xv.x - mu, d1 = xv.y - mu, d2 = xv.z - mu, d3 = xv.w - mu;
  float q = d0 * d0 + d1 * d1 + d2 * d2 + d3 * d3;
  q = block_sum(q);
  const float rstd = rsqrtf(q * (1.0f / 1024.0f) + 1e-5f);
  const float4 gv = ((const float4*)g)[tid];
  const float4 bv = ((const float4*)b)[tid];
  unsigned short* o = out + (size_t)row * 1024 + tid * 4;
  o[0] = f2bf(d0 * rstd * gv.x + bv.x);
  o[1] = f2bf(d1 * rstd * gv.y + bv.y);
  o[2] = f2bf(d2 * rstd * gv.z + bv.z);
  o[3] = f2bf(d3 * rstd * gv.w + bv.w);
}

// transpose-cast body: in[K][N] fp32 -> out[N][K] bf16, one 64x64 tile
__device__ __forceinline__ void tc_body(const float* __restrict__ in,
                                        unsigned short* __restrict__ out,
                                        int K, int N, int bx, int by) {
  __shared__ unsigned short L[64][65];
  const int t = threadIdx.x;
  const int k0 = by * 64, n0 = bx * 64;
  const int r = t >> 4, c4 = (t & 15) * 4;
  #pragma unroll
  for (int rr = 0; rr < 4; ++rr) {
    const int kk = rr * 16 + r;
    const float4 f = ((const float4*)(in + (size_t)(k0 + kk) * N + n0))[t & 15];
    L[kk][c4 + 0] = f2bf(f.x); L[kk][c4 + 1] = f2bf(f.y);
    L[kk][c4 + 2] = f2bf(f.z); L[kk][c4 + 3] = f2bf(f.w);
  }
  __syncthreads();
  #pragma unroll
  for (int rr = 0; rr < 4; ++rr) {
    const int nn = rr * 16 + r;
    ushort4 u;
    u.x = L[c4 + 0][nn]; u.y = L[c4 + 1][nn];
    u.z = L[c4 + 2][nn]; u.w = L[c4 + 3][nn];
    ((ushort4*)(out + (size_t)(n0 + nn) * K + k0))[t & 15] = u;
  }
}

// fused prep: W_h^T (1024 blocks), W_qk^T (32), W_out^T (512), bias table (2)
__global__ __launch_bounds__(256) void prep_k(const float* __restrict__ W_h,
                                              const float* __restrict__ W_qk,
                                              const float* __restrict__ W_out,
                                              const float* __restrict__ rel,
                                              unsigned short* __restrict__ whT,
                                              unsigned short* __restrict__ wqkT,
                                              unsigned short* __restrict__ woutT,
                                              float* __restrict__ tab) {
  const int b = blockIdx.x;
  if (b < 1024) {
    tc_body(W_h, whT, 1024, 4096, b & 63, b >> 6);
  } else if (b < 1056) {
    const int c = b - 1024;
    tc_body(W_qk, wqkT, 1024, 128, c & 1, c >> 1);
  } else if (b < 1568) {
    const int c = b - 1056;
    tc_body(W_out, woutT, 2048, 1024, c & 15, c >> 4);
  } else {
    int idx = (b - 1568) * 256 + threadIdx.x;
    if (idx >= 511) return;
    int d = idx - 255;       // j - i
    int n = -d;              // i - j
    int ret = (n < 0) ? 16 : 0;
    int a = (n < 0) ? -n : n;
    int bucket;
    if (a < 8) {
      bucket = ret + a;
    } else {
      float t = __logf((float)a * 0.125f) / 2.7725887298583984f * 8.0f;
      int vl = 8 + (int)t;
      if (vl > 15) vl = 15;
      bucket = ret + vl;
    }
    tab[idx] = rel[bucket] * 11.313708498984761f;  // * sqrt(QK)
  }
}

// reduce 4 split-K partials of pkvT[b][s][e][d], scale 1/N, cast -> linkvT[b][e][d]
__global__ void kvred_k(const float* __restrict__ pkv, unsigned short* __restrict__ linkvT) {
  int i4 = blockIdx.x * 256 + threadIdx.x;   // < 262144 (float4 units)
  const int b = i4 >> 16, rem = i4 & 65535;
  const float4* p = (const float4*)(pkv + (size_t)b * 1048576) + rem;
  const float4 p0 = p[0], p1 = p[65536], p2 = p[131072], p3 = p[196608];
  ushort4 u;
  u.x = f2bf((p0.x + p1.x + p2.x + p3.x) * (1.0f / 4096.0f));
  u.y = f2bf((p0.y + p1.y + p2.y + p3.y) * (1.0f / 4096.0f));
  u.z = f2bf((p0.z + p1.z + p2.z + p3.z) * (1.0f / 4096.0f));
  u.w = f2bf((p0.w + p1.w + p2.w + p3.w) * (1.0f / 4096.0f));
  ((ushort4*)(linkvT + (size_t)b * 262144))[rem] = u;
}

// ---------------------------------------------------------------------------
// 256x256 tile software-pipelined GEMM. C = A(MxK) @ B(NxK)^T, bf16.
// MODE 0: hid   M=16384 N=4096 K=1024 (kiters=32); epi silu(+b_h) -> vT | gate
// MODE 3: quad+lin per-group: M=256(group) N=2048, K=256(attn@vT, t<8) +
//         128(lq@linkvT, t>=8) -> kiters=12; grid (8,64)=(e-tile, group);
//         epi *gate. No remap (no cross-block B reuse).
// MODE 6: final M=16384 N=1024 K=2048 (kiters=64); epi +b_out +x -> fp32 out
//
// Block remap (modes 0/6; gridDim.y==64): L = bx + gridDim.x*by; p = L&7
// (XCD); s = L>>3; bm=(p*8+(s&7))*256; bn=(s>>3)*256. Bijective.
//
// Per-tile schedule (steady state), all C++ ds_reads (compiler manages lgkm):
//   gate vmcnt(4) -> tile t+1 landed; asm s_barrier; stage(t+3);
//   12 ds_read_b128 of tile t+1 into NXT regs; sched_barrier(0);
//   32 MFMA on CUR regs (counted lgkm keeps NXT reads in flight).
// Register double-buffer via x2 loop unroll (kiters even: 32 / 12 / 64).
// ---------------------------------------------------------------------------
template<int MODE>
__global__ __launch_bounds__(512, 2) void gemm256_k(
    const unsigned short* __restrict__ Ag,
    const unsigned short* __restrict__ Bg,
    int lda, int ldb, int kiters, Aux aux)
{
  extern __shared__ __align__(16) char smem[];   // 4 slots x (16K A + 16K B)

  const int tid  = threadIdx.x;
  const int lane = tid & 63;
  const int wave = tid >> 6;
  const int quad = lane >> 4;
  const int l16  = lane & 15;
  const int wm   = (wave >> 2) * 128;   // 2 M-waves
  const int wn   = (wave & 3) * 64;     // 4 N-waves

  int bm, bn, g = 0;
  if constexpr (MODE == 3) {
    g  = blockIdx.y;            // group (64)
    bm = 0;                     // group-local rows 0..255
    bn = blockIdx.x * 256;      // e-tile (8)
  } else {
    const int L  = blockIdx.x + gridDim.x * blockIdx.y;
    const int p  = L & 7;
    const int s  = L >> 3;
    bm = (p * 8 + (s & 7)) * 256;
    bn = (s >> 3) * 256;
  }

  const size_t lda2 = (size_t)lda * 2;
  const size_t ldb2 = (size_t)ldb * 2;

  // Staging: linear LDS dest (global_load_lds requirement) + inverse-swizzled
  // global SOURCE; read side applies the same swizzle (rule #21).
  const int srow  = tid >> 2;
  const int scolb = ((tid & 3) ^ ((tid >> 3) & 3)) << 4;
  const char *gA, *gB, *gA2 = nullptr, *gB2 = nullptr;
  if constexpr (MODE == 3) {
    // A  = attn[g]   : 256x256, row 512 B      A2 = lq[g]     : 256x128, row 256 B
    // B  = vT[b]     : rows e, t-window (g&15)*256, row 8192 B
    // B2 = linkvT[b] : rows e, row 256 B
    gA  = (const char*)Ag + (size_t)g * 131072 + (size_t)srow * 512 + scolb;
    gA2 = (const char*)aux.a2 + (size_t)g * 65536 + (size_t)srow * 256 + scolb;
    gB  = (const char*)Bg + (size_t)(g >> 4) * 16777216 + (size_t)(g & 15) * 512
          + (size_t)(bn + srow) * 8192 + scolb;
    gB2 = (const char*)aux.bkv + (size_t)(g >> 4) * 524288
          + (size_t)(bn + srow) * 256 + scolb;
  } else {
    gA = (const char*)Ag + (size_t)(bm + srow) * lda2 + scolb;
    gB = (const char*)Bg + (size_t)(bn + srow) * ldb2 + scolb;
  }
  char* laBase = smem + wave * 1024;    // wave-uniform LDS base (HW adds lane*16)

  auto stage = [&](int tt) {
    char* la = laBase + (tt & 3) * 32768;
    const char *a, *b; size_t sA, sB;
    if constexpr (MODE == 3) {
      if (tt >= 8) { a = gA2 + (size_t)(tt - 8) * 64; sA = 256;
                     b = gB2 + (size_t)(tt - 8) * 64; sB = 256; }
      else         { a = gA  + (size_t)tt * 64;       sA = 512;
                     b = gB  + (size_t)tt * 64;       sB = 8192; }
    } else {
      a = gA + (size_t)tt * 64; sA = lda2;
      b = gB + (size_t)tt * 64; sB = ldb2;
    }
    async_cp16(a,            la);            // A rows   0..127
    async_cp16(a + 128 * sA, la + 8192);     // A rows 128..255
    async_cp16(b,            la + 16384);    // B rows   0..127
    async_cp16(b + 128 * sB, la + 24576);    // B rows 128..255
  };

  const f32x4 zero = {0.f, 0.f, 0.f, 0.f};
  f32x4 acc[8][4];
  #pragma unroll
  for (int i = 0; i < 8; ++i)
    #pragma unroll
    for (int j = 0; j < 4; ++j) acc[i][j] = zero;

  // prologue: 3 tiles in flight (kiters >= 3 for all uses)
  stage(0); stage(1); stage(2);

  // read-side base pointers; frag (i) at rd* + slot + i*1024; swizzle window
  // cw folds to a per-thread constant (row>>1)&3 == (l16>>1)&3 for all frags.
  const int cw = (quad ^ ((l16 >> 1) & 3)) << 4;
  const char* rdA = smem + (wm + l16) * 64 + cw;
  const char* rdB = smem + 16384 + (wn + l16) * 64 + cw;

  short8 fA[12], fB[12];   // [0..7]=A frags, [8..11]=B frags

  // prologue gate: tile 0 landed (tiles 1,2 = 8 loads stay in flight)
  asm volatile("s_waitcnt vmcnt(8)" ::: "memory");
  asm volatile("s_barrier" ::: "memory");
  #pragma unroll
  for (int i = 0; i < 8; ++i) fA[i]     = *(const short8*)(rdA + i * 1024);
  #pragma unroll
  for (int j = 0; j < 4; ++j) fA[8 + j] = *(const short8*)(rdB + j * 1024);

#define TILE_BODY(T, CUR, NXT)                                                 \
  do {                                                                         \
    const int t_ = (T);                                                        \
    if (t_ + 1 < kiters) {                                                     \
      if (t_ + 2 < kiters) asm volatile("s_waitcnt vmcnt(4)" ::: "memory");    \
      else                 asm volatile("s_waitcnt vmcnt(0)" ::: "memory");    \
    }                                                                          \
    asm volatile("s_barrier" ::: "memory");                                    \
    if (t_ + 3 < kiters) stage(t_ + 3);                                        \
    if (t_ + 1 < kiters) {                                                     \
      const unsigned s1 = (unsigned)((t_ + 1) & 3) * 32768u;                   \
      _Pragma("unroll")                                                        \
      for (int i = 0; i < 8; ++i)                                              \
        NXT[i]     = *(const short8*)(rdA + s1 + i * 1024);                    \
      _Pragma("unroll")                                                        \
      for (int j = 0; j < 4; ++j)                                              \
        NXT[8 + j] = *(const short8*)(rdB + s1 + j * 1024);                    \
    }                                                                          \
    __builtin_amdgcn_sched_barrier(0);                                         \
    __builtin_amdgcn_s_setprio(1);                                             \
    _Pragma("unroll")                                                          \
    for (int i = 0; i < 8; ++i)                                                \
      _Pragma("unroll")                                                        \
      for (int j = 0; j < 4; ++j)                                              \
        acc[i][j] = __builtin_amdgcn_mfma_f32_16x16x32_bf16(                   \
            CUR[i], CUR[8 + j], acc[i][j], 0, 0, 0);                           \
    __builtin_amdgcn_s_setprio(0);                                             \
    __builtin_amdgcn_sched_barrier(0);                                         \
  } while (0)

  for (int t = 0; t < kiters; t += 2) {   // kiters even (32 / 12 / 64)
    TILE_BODY(t,     fA, fB);
    TILE_BODY(t + 1, fB, fA);
  }
#undef TILE_BODY

  // epilogue (no LDS use): D[row=quad*4+r][col=l16] per 16x16 tile
  #pragma unroll
  for (int i = 0; i < 8; ++i) {
    #pragma unroll
    for (int j = 0; j < 4; ++j) {
      const int row0 = bm + wm + i * 16 + quad * 4;
      const int col  = bn + wn + j * 16 + l16;
      if constexpr (MODE == 0) {
        const float bb = aux.b1[col];
        float s4[4];
        #pragma unroll
        for (int r = 0; r < 4; ++r) s4[r] = silu_f(acc[i][j][r] + bb);
        if (bn < 2048) {           // vT[b][e][t] (uniform per block)
          const int b = row0 >> 12, tt = row0 & 4095;
          ushort4 u; u.x = f2bf(s4[0]); u.y = f2bf(s4[1]); u.z = f2bf(s4[2]); u.w = f2bf(s4[3]);
          *(ushort4*)(aux.o16a + (size_t)b * 8388608 + (size_t)col * 4096 + tt) = u;
        } else {                   // gate row-major
          #pragma unroll
          for (int r = 0; r < 4; ++r)
            aux.o16b[(size_t)(row0 + r) * 2048 + (col - 2048)] = f2bf(s4[r]);
        }
      } else if constexpr (MODE == 3) {
        #pragma unroll
        for (int r = 0; r < 4; ++r) {
          const size_t idx = ((size_t)g * 256 + row0 + r) * 2048 + col;
          aux.o16a[idx] = f2bf(acc[i][j][r] * bf2f(aux.gate[idx]));
        }
      } else {  // MODE == 6
        #pragma unroll
        for (int r = 0; r < 4; ++r) {
          const size_t idx = (size_t)(row0 + r) * 1024 + col;
          aux.o32[idx] = acc[i][j][r] + aux.b1[col] + aux.x[idx];
        }
      }
    }
  }
}

// ---------------------------------------------------------------------------
// 128x128 kernel, kept for modes 1,2,4.
// MODE 1: qk    M=16384 N=128  K=1024; epi silu(+b_qk): qq/lq/qkk + linkT
// MODE 2: sim   per-group M=N=256 K=128; epi /G +bias, relu^2 -> attn
// MODE 4: lin_kv split-K x4 per batch M=128(d) N=2048(e) K=1024; epi fp32 pkvT
// ---------------------------------------------------------------------------
template<int MODE>
__global__ __launch_bounds__(256, 2) void gemm_k(
    const unsigned short* __restrict__ Ag,
    const unsigned short* __restrict__ Bg,
    int lda, int ldb, int kiters, Aux aux)
{
  __shared__ unsigned short As[BM * BK];
  __shared__ unsigned short Bs[BN * BK];

  const int tid  = threadIdx.x;
  const int lane = tid & 63;
  const int wave = tid >> 6;
  const int quad = lane >> 4;
  const int l16  = lane & 15;
  const int wm   = (wave >> 1) * 64;
  const int wn   = (wave & 1) * 64;
  const int bz   = blockIdx.z;
  const int bm   = blockIdx.y * BM;
  const int bn   = blockIdx.x * BN;

  const unsigned short* A = Ag;
  const unsigned short* B = Bg;
  if constexpr (MODE == 2) { A += (size_t)bz * 32768;  B += (size_t)bz * 32768; }
  if constexpr (MODE == 4) { const int b = bz >> 2, s = bz & 3;
                             A += (size_t)b * 524288 + (size_t)s * 1024;    // linkT cols s*1024..
                             B += (size_t)b * 8388608 + (size_t)s * 1024; } // vT cols s*1024..

  const int srow = wave * 32 + (lane >> 2);  // staging row (+16 for 2nd issue)
  const int scol = (lane & 3) * 8;           // staging col (8 bf16 = 16B)
  unsigned short* lA = As + wave * 1024;     // wave-uniform LDS bases
  unsigned short* lB = Bs + wave * 1024;

  const f32x4 zero = {0.f, 0.f, 0.f, 0.f};
  f32x4 acc[4][4];
  #pragma unroll
  for (int i = 0; i < 4; ++i)
    #pragma unroll
    for (int j = 0; j < 4; ++j) acc[i][j] = zero;

  for (int kt = 0; kt < kiters; ++kt) {
    const int kk = kt * BK;

    __syncthreads();  // prior iteration's LDS reads complete
    async_cp16(A + (size_t)(bm + srow) * lda + kk + scol, lA);
    async_cp16(A + (size_t)(bm + srow + 16) * lda + kk + scol, lA + 512);
    async_cp16(B + (size_t)(bn + srow) * ldb + kk + scol, lB);
    async_cp16(B + (size_t)(bn + srow + 16) * ldb + kk + scol, lB + 512);
    __syncthreads();  // drains vmcnt (compiler) -> staged data visible

    short8 af[4], bfv[4];
    #pragma unroll
    for (int i = 0; i < 4; ++i)
      af[i] = *reinterpret_cast<const short8*>(As + (wm + i * 16 + l16) * BK + quad * 8);
    #pragma unroll
    for (int j = 0; j < 4; ++j)
      bfv[j] = *reinterpret_cast<const short8*>(Bs + (wn + j * 16 + l16) * BK + quad * 8);

    #pragma unroll
    for (int i = 0; i < 4; ++i)
      #pragma unroll
      for (int j = 0; j < 4; ++j)
        acc[i][j] = __builtin_amdgcn_mfma_f32_16x16x32_bf16(af[i], bfv[j], acc[i][j], 0, 0, 0);
  }

  // epilogue: D[row=quad*4+r][col=l16] per 16x16 tile
  #pragma unroll
  for (int i = 0; i < 4; ++i) {
    #pragma unroll
    for (int j = 0; j < 4; ++j) {
      const int row0 = bm + wm + i * 16 + quad * 4;
      const int col  = bn + wn + j * 16 + l16;
      if constexpr (MODE == 1) {
        const float bb = aux.b1[col];
        float s[4];
        #pragma unroll
        for (int r = 0; r < 4; ++r) s[r] = silu_f(acc[i][j][r] + bb);
        #pragma unroll
        for (int r = 0; r < 4; ++r) {
          const size_t idx = (size_t)(row0 + r) * 128 + col;
          aux.o16a[idx] = f2bf(s[r] * aux.gamma[col]       + aux.beta[col]);        // quad_q
          aux.o16b[idx] = f2bf(s[r] * aux.gamma[128 + col] + aux.beta[128 + col]);  // lin_q
          aux.o16c[idx] = f2bf(s[r] * aux.gamma[256 + col] + aux.beta[256 + col]);  // quad_k
        }
        const int b = row0 >> 12, t = row0 & 4095;                                  // lin_k^T
        const float g4 = aux.gamma[384 + col], b4 = aux.beta[384 + col];
        ushort4 u;
        u.x = f2bf(s[0] * g4 + b4); u.y = f2bf(s[1] * g4 + b4);
        u.z = f2bf(s[2] * g4 + b4); u.w = f2bf(s[3] * g4 + b4);
        *(ushort4*)(aux.o16d + (size_t)b * 524288 + (size_t)col * 4096 + t) = u;
      } else if constexpr (MODE == 2) {
        #pragma unroll
        for (int r = 0; r < 4; ++r) {
          float s = acc[i][j][r] * (1.0f / 256.0f) + aux.biastab[col - (row0 + r) + 255];
          s = fmaxf(s, 0.0f);
          aux.o16a[(size_t)bz * 65536 + (size_t)(row0 + r) * 256 + col] = f2bf(s * s);
        }
      } else if constexpr (MODE == 4) {
        float4 u; u.x = acc[i][j][0]; u.y = acc[i][j][1]; u.z = acc[i][j][2]; u.w = acc[i][j][3];
        *(float4*)(aux.o32 + (size_t)bz * 262144 + (size_t)col * 128 + row0) = u;
      }
    }
  }
}

extern "C" void kernel_launch(void* const* d_in, const int* in_sizes, int n_in,
                              void* d_out, int out_size, void* d_ws, size_t ws_size,
                              hipStream_t stream) {
  (void)in_sizes; (void)n_in; (void)out_size; (void)ws_size;
  const float* x     = (const float*)d_in[0];
  const float* ln_g  = (const float*)d_in[1];
  const float* ln_b  = (const float*)d_in[2];
  const float* W_h   = (const float*)d_in[3];
  const float* b_h   = (const float*)d_in[4];
  const float* W_qk  = (const float*)d_in[5];
  const float* b_qk  = (const float*)d_in[6];
  const float* osg   = (const float*)d_in[7];
  const float* osb   = (const float*)d_in[8];
  const float* rel   = (const float*)d_in[9];
  const float* W_out = (const float*)d_in[10];
  const float* b_out = (const float*)d_in[11];
  float* out = (float*)d_out;

  // 128 KiB dynamic LDS for the 256x256 pipelined kernels (one-time).
  static bool attr_done = false;
  if (!attr_done) {
    hipFuncSetAttribute(reinterpret_cast<const void*>(gemm256_k<0>),
                        hipFuncAttributeMaxDynamicSharedMemorySize, 131072);
    hipFuncSetAttribute(reinterpret_cast<const void*>(gemm256_k<3>),
                        hipFuncAttributeMaxDynamicSharedMemorySize, 131072);
    hipFuncSetAttribute(reinterpret_cast<const void*>(gemm256_k<6>),
                        hipFuncAttributeMaxDynamicSharedMemorySize, 131072);
    attr_done = true;
  }

  char* w = (char*)d_ws;
  size_t off = 0;
  auto alloc = [&](size_t bytes) { char* p = w + off; off += (bytes + 255) & ~(size_t)255; return p; };

  // ---- arena R (all dead before mode 3 writes `gated`, which aliases R) ----
  unsigned short* normed = (unsigned short*)alloc(16384ull * 1024 * 2);   // 32M, dead after mode1
  unsigned short* whT    = (unsigned short*)alloc(4096ull * 1024 * 2);    //  8M, dead after mode0
  unsigned short* qq     = (unsigned short*)alloc(16384ull * 128 * 2);    //  4M, dead after mode2
  unsigned short* qkk    = (unsigned short*)alloc(16384ull * 128 * 2);    //  4M, dead after mode2
  unsigned short* linkT  = (unsigned short*)alloc(4ull * 128 * 4096 * 2); //  4M, dead after mode4
  float*          pkvT   = (float*)alloc(16ull * 2048 * 128 * 4);         // 16M, dead after kvred
  unsigned short* wqkT   = (unsigned short*)alloc(128ull * 1024 * 2);     // 256K, dead after mode1
  // ---- live-through buffers ----
  unsigned short* woutT  = (unsigned short*)alloc(1024ull * 2048 * 2);
  unsigned short* vT     = (unsigned short*)alloc(4ull * 2048 * 4096 * 2); // 64M
  unsigned short* gate   = (unsigned short*)alloc(16384ull * 2048 * 2);    // 64M
  unsigned short* lq     = (unsigned short*)alloc(16384ull * 128 * 2);
  unsigned short* attn   = (unsigned short*)alloc(64ull * 256 * 256 * 2);  //  8M
  unsigned short* linkvT = (unsigned short*)alloc(4ull * 2048 * 128 * 2);
  float*          btab   = (float*)alloc(511 * 4);
  unsigned short* gated  = (unsigned short*)w;  // alias arena R (64M needed, ~68M there)

  prep_k<<<1570, 256, 0, stream>>>(W_h, W_qk, W_out, rel, whT, wqkT, woutT, btab);
  ln_k<<<16384, 256, 0, stream>>>(x, ln_g, ln_b, normed);

  Aux a0{}; a0.b1 = b_h; a0.o16a = vT; a0.o16b = gate;
  gemm256_k<0><<<dim3(16, 64), 512, 131072, stream>>>(normed, whT, 1024, 1024, 32, a0);

  Aux a1{}; a1.b1 = b_qk; a1.gamma = osg; a1.beta = osb;
  a1.o16a = qq; a1.o16b = lq; a1.o16c = qkk; a1.o16d = linkT;
  gemm_k<1><<<dim3(1, 128, 1), 256, 0, stream>>>(normed, wqkT, 1024, 1024, 32, a1);

  Aux a2x{}; a2x.biastab = btab; a2x.o16a = attn;
  gemm_k<2><<<dim3(2, 2, 64), 256, 0, stream>>>(qq, qkk, 128, 128, 4, a2x);

  Aux a4{}; a4.o32 = pkvT;
  gemm_k<4><<<dim3(16, 1, 16), 256, 0, stream>>>(linkT, vT, 4096, 4096, 8, a4);

  kvred_k<<<1024, 256, 0, stream>>>(pkvT, linkvT);

  Aux a3{}; a3.a2 = lq; a3.bkv = linkvT; a3.gate = gate; a3.o16a = gated;
  gemm256_k<3><<<dim3(8, 64), 512, 131072, stream>>>(attn, vT, 256, 4096, 12, a3);

  Aux a6{}; a6.b1 = b_out; a6.x = x; a6.o32 = out;
  gemm256_k<6><<<dim3(4, 64), 512, 131072, stream>>>(gated, woutT, 2048, 2048, 64, a6);
}

// Round 9
// 572.463 us; speedup vs baseline: 1.7856x; 1.0636x over previous
//
#include <hip/hip_runtime.h>
#include <hip/hip_bf16.h>

// FLASH/GAU block: B=4 N=4096 DIM=1024 QK=128 G=256, all GEMMs in TN form
// (A: MxK row-major, B: NxK row-major, K contiguous).
// Big GEMMs (mode 0 hid, mode 6 final): 256x256 tile, BK=32, 8 waves, 4-slot
// pipelined LDS (128 KiB), XOR-swizzled LDS reads, counted vmcnt gates,
// one-tile-ahead register prefetch, XCD/L2-locality block remap (each XCD
// owns 8 A-panels = 4 MB = L2 size; x-outer order keeps B-panel hot).
// [round-4 verified configuration: 573.7 us total, mode-0 = 193 us]
// Modes 1,2,3,4: 128x128 m97-structure kernel (mode 3 = per-K-segment
// source switch attn@vT / lq@linkvT). prep_k fuses the 3 weight transposes
// + bias table into one launch (the single delta vs round 4).

typedef __attribute__((ext_vector_type(8))) short short8;
typedef __attribute__((ext_vector_type(4))) float f32x4;

#define BM 128
#define BN 128
#define BK 32

struct Aux {
  const float* b1;              // bias vec (b_h / b_qk / b_out)
  const float* x;               // residual (mode6)
  const float* gamma;           // os_gamma (mode1)
  const float* beta;            // os_beta  (mode1)
  const float* biastab;         // rel-pos table (mode2)
  const unsigned short* a2;     // mode3 tail A: lin_q (16384x128)
  const unsigned short* bkv;    // mode3 tail B: linkvT (4x2048x128)
  const unsigned short* gate;   // mode3: bf16 gate
  unsigned short* o16a;
  unsigned short* o16b;
  unsigned short* o16c;
  unsigned short* o16d;
  float* o32;
};

__device__ __forceinline__ float bf2f(unsigned short u) {
  union { float f; unsigned int i; } w; w.i = ((unsigned int)u) << 16; return w.f;
}
__device__ __forceinline__ unsigned short f2bf(float f) {
  union { float f; unsigned int i; } w; w.f = f;
  unsigned int x = w.i;
  return (unsigned short)((x + 0x7FFFu + ((x >> 16) & 1u)) >> 16);
}
__device__ __forceinline__ float silu_f(float z) { return z / (1.0f + __expf(-z)); }

// async global->LDS, 16B per lane; lptr must be the wave-uniform base
__device__ __forceinline__ void async_cp16(const void* g, void* l) {
  __builtin_amdgcn_global_load_lds(
      (const __attribute__((address_space(1))) void*)g,
      (__attribute__((address_space(3))) void*)l, 16, 0, 0);
}

__device__ __forceinline__ float block_sum(float v) {
  #pragma unroll
  for (int o = 32; o > 0; o >>= 1) v += __shfl_down(v, o, 64);
  __shared__ float sh[4];
  __syncthreads();
  if ((threadIdx.x & 63) == 0) sh[threadIdx.x >> 6] = v;
  __syncthreads();
  return sh[0] + sh[1] + sh[2] + sh[3];
}

// LayerNorm over DIM=1024, one block per row, output bf16.
__global__ __launch_bounds__(256) void ln_k(const float* __restrict__ x,
                                            const float* __restrict__ g,
                                            const float* __restrict__ b,
                                            unsigned short* __restrict__ out) {
  const int row = blockIdx.x;
  const int tid = threadIdx.x;
  const float4 xv = ((const float4*)(x + (size_t)row * 1024))[tid];
  float s = xv.x + xv.y + xv.z + xv.w;
  s = block_sum(s);
  const float mu = s * (1.0f / 1024.0f);
  const float d0 = xv.x - mu, d1 = xv.y - mu, d2 = xv.z - mu, d3 = xv.w - mu;
  float q = d0 * d0 + d1 * d1 + d2 * d2 + d3 * d3;
  q = block_sum(q);
  const float rstd = rsqrtf(q * (1.0f / 1024.0f) + 1e-5f);
  const float4 gv = ((const float4*)g)[tid];
  const float4 bv = ((const float4*)b)[tid];
  unsigned short* o = out + (size_t)row * 1024 + tid * 4;
  o[0] = f2bf(d0 * rstd * gv.x + bv.x);
  o[1] = f2bf(d1 * rstd * gv.y + bv.y);
  o[2] = f2bf(d2 * rstd * gv.z + bv.z);
  o[3] = f2bf(d3 * rstd * gv.w + bv.w);
}

// transpose-cast body: in[K][N] fp32 -> out[N][K] bf16, one 64x64 tile
__device__ __forceinline__ void tc_body(const float* __restrict__ in,
                                        unsigned short* __restrict__ out,
                                        int K, int N, int bx, int by) {
  __shared__ unsigned short L[64][65];
  const int t = threadIdx.x;
  const int k0 = by * 64, n0 = bx * 64;
  const int r = t >> 4, c4 = (t & 15) * 4;
  #pragma unroll
  for (int rr = 0; rr < 4; ++rr) {
    const int kk = rr * 16 + r;
    const float4 f = ((const float4*)(in + (size_t)(k0 + kk) * N + n0))[t & 15];
    L[kk][c4 + 0] = f2bf(f.x); L[kk][c4 + 1] = f2bf(f.y);
    L[kk][c4 + 2] = f2bf(f.z); L[kk][c4 + 3] = f2bf(f.w);
  }
  __syncthreads();
  #pragma unroll
  for (int rr = 0; rr < 4; ++rr) {
    const int nn = rr * 16 + r;
    ushort4 u;
    u.x = L[c4 + 0][nn]; u.y = L[c4 + 1][nn];
    u.z = L[c4 + 2][nn]; u.w = L[c4 + 3][nn];
    ((ushort4*)(out + (size_t)(n0 + nn) * K + k0))[t & 15] = u;
  }
}

// fused prep: W_h^T (1024 blocks), W_qk^T (32), W_out^T (512), bias table (2)
__global__ __launch_bounds__(256) void prep_k(const float* __restrict__ W_h,
                                              const float* __restrict__ W_qk,
                                              const float* __restrict__ W_out,
                                              const float* __restrict__ rel,
                                              unsigned short* __restrict__ whT,
                                              unsigned short* __restrict__ wqkT,
                                              unsigned short* __restrict__ woutT,
                                              float* __restrict__ tab) {
  const int b = blockIdx.x;
  if (b < 1024) {
    tc_body(W_h, whT, 1024, 4096, b & 63, b >> 6);
  } else if (b < 1056) {
    const int c = b - 1024;
    tc_body(W_qk, wqkT, 1024, 128, c & 1, c >> 1);
  } else if (b < 1568) {
    const int c = b - 1056;
    tc_body(W_out, woutT, 2048, 1024, c & 15, c >> 4);
  } else {
    int idx = (b - 1568) * 256 + threadIdx.x;
    if (idx >= 511) return;
    int d = idx - 255;       // j - i
    int n = -d;              // i - j
    int ret = (n < 0) ? 16 : 0;
    int a = (n < 0) ? -n : n;
    int bucket;
    if (a < 8) {
      bucket = ret + a;
    } else {
      float t = __logf((float)a * 0.125f) / 2.7725887298583984f * 8.0f;
      int vl = 8 + (int)t;
      if (vl > 15) vl = 15;
      bucket = ret + vl;
    }
    tab[idx] = rel[bucket] * 11.313708498984761f;  // * sqrt(QK)
  }
}

// reduce 4 split-K partials of pkvT[b][s][e][d], scale 1/N, cast -> linkvT[b][e][d]
__global__ void kvred_k(const float* __restrict__ pkv, unsigned short* __restrict__ linkvT) {
  int i4 = blockIdx.x * 256 + threadIdx.x;   // < 262144 (float4 units)
  const int b = i4 >> 16, rem = i4 & 65535;
  const float4* p = (const float4*)(pkv + (size_t)b * 1048576) + rem;
  const float4 p0 = p[0], p1 = p[65536], p2 = p[131072], p3 = p[196608];
  ushort4 u;
  u.x = f2bf((p0.x + p1.x + p2.x + p3.x) * (1.0f / 4096.0f));
  u.y = f2bf((p0.y + p1.y + p2.y + p3.y) * (1.0f / 4096.0f));
  u.z = f2bf((p0.z + p1.z + p2.z + p3.z) * (1.0f / 4096.0f));
  u.w = f2bf((p0.w + p1.w + p2.w + p3.w) * (1.0f / 4096.0f));
  ((ushort4*)(linkvT + (size_t)b * 262144))[rem] = u;
}

// ---------------------------------------------------------------------------
// 256x256 tile software-pipelined GEMM for the two big matmuls.
// C = A(MxK) @ B(NxK)^T, bf16 inputs, K contiguous.
// MODE 0: hid   M=16384 N=4096 K=1024 (kiters=32); epi silu(+b_h) -> vT | gate
// MODE 6: final M=16384 N=1024 K=2048 (kiters=64); epi +b_out +x -> fp32 out
//
// Block remap for L2 locality (gridDim.y == 64): L = bx + gridDim.x*by;
// p = L&7 (XCD); s = L>>3; bm=(p*8+(s&7))*256; bn=(s>>3)*256. Bijective.
// Each XCD owns M-rows [8p,8p+8): 8 A-panels (4 MB) fit its L2; x-outer
// order keeps one B-panel hot while A-panels cycle.
//
// Per-tile schedule (steady state), all C++ ds_reads (compiler manages lgkm):
//   gate vmcnt(4) -> tile t+1 landed; asm s_barrier; stage(t+3);
//   12 ds_read_b128 of tile t+1 into NXT regs; sched_barrier(0);
//   32 MFMA on CUR regs (counted lgkm keeps NXT reads in flight).
// Register double-buffer via x2 loop unroll (kiters even: 32 / 64).
// ---------------------------------------------------------------------------
template<int MODE>
__global__ __launch_bounds__(512, 2) void gemm256_k(
    const unsigned short* __restrict__ Ag,
    const unsigned short* __restrict__ Bg,
    int lda, int ldb, int kiters, Aux aux)
{
  extern __shared__ __align__(16) char smem[];   // 4 slots x (16K A + 16K B)

  const int tid  = threadIdx.x;
  const int lane = tid & 63;
  const int wave = tid >> 6;
  const int quad = lane >> 4;
  const int l16  = lane & 15;
  const int wm   = (wave >> 2) * 128;   // 2 M-waves
  const int wn   = (wave & 3) * 64;     // 4 N-waves

  // XCD/L2-locality block remap (bijective; gridDim.y==64 for both modes)
  const int L  = blockIdx.x + gridDim.x * blockIdx.y;
  const int p  = L & 7;
  const int s  = L >> 3;
  const int bm = (p * 8 + (s & 7)) * 256;
  const int bn = (s >> 3) * 256;

  const size_t lda2 = (size_t)lda * 2;
  const size_t ldb2 = (size_t)ldb * 2;

  // Staging: linear LDS dest (global_load_lds requirement) + inverse-swizzled
  // global SOURCE; read side applies the same swizzle (rule #21).
  const int srow  = tid >> 2;
  const int scolb = ((tid & 3) ^ ((tid >> 3) & 3)) << 4;
  const char* gA = (const char*)Ag + (size_t)(bm + srow) * lda2 + scolb;
  const char* gB = (const char*)Bg + (size_t)(bn + srow) * ldb2 + scolb;
  char* laBase = smem + wave * 1024;    // wave-uniform LDS base (HW adds lane*16)

  auto stage = [&](int tt) {
    char* la = laBase + (tt & 3) * 32768;
    const char* a = gA + (size_t)tt * 64;
    const char* b = gB + (size_t)tt * 64;
    async_cp16(a,              la);            // A rows   0..127
    async_cp16(a + 128 * lda2, la + 8192);     // A rows 128..255
    async_cp16(b,              la + 16384);    // B rows   0..127
    async_cp16(b + 128 * ldb2, la + 24576);    // B rows 128..255
  };

  const f32x4 zero = {0.f, 0.f, 0.f, 0.f};
  f32x4 acc[8][4];
  #pragma unroll
  for (int i = 0; i < 8; ++i)
    #pragma unroll
    for (int j = 0; j < 4; ++j) acc[i][j] = zero;

  // prologue: 3 tiles in flight (kiters >= 3 for all uses)
  stage(0); stage(1); stage(2);

  // read-side base pointers; frag (i) at rd* + slot + i*1024; swizzle window
  // cw folds to a per-thread constant (row>>1)&3 == (l16>>1)&3 for all frags.
  const int cw = (quad ^ ((l16 >> 1) & 3)) << 4;
  const char* rdA = smem + (wm + l16) * 64 + cw;
  const char* rdB = smem + 16384 + (wn + l16) * 64 + cw;

  short8 fA[12], fB[12];   // [0..7]=A frags, [8..11]=B frags

  // prologue gate: tile 0 landed (tiles 1,2 = 8 loads stay in flight)
  asm volatile("s_waitcnt vmcnt(8)" ::: "memory");
  asm volatile("s_barrier" ::: "memory");
  #pragma unroll
  for (int i = 0; i < 8; ++i) fA[i]     = *(const short8*)(rdA + i * 1024);
  #pragma unroll
  for (int j = 0; j < 4; ++j) fA[8 + j] = *(const short8*)(rdB + j * 1024);

#define TILE_BODY(T, CUR, NXT)                                                 \
  do {                                                                         \
    const int t_ = (T);                                                        \
    if (t_ + 1 < kiters) {                                                     \
      if (t_ + 2 < kiters) asm volatile("s_waitcnt vmcnt(4)" ::: "memory");    \
      else                 asm volatile("s_waitcnt vmcnt(0)" ::: "memory");    \
    }                                                                          \
    asm volatile("s_barrier" ::: "memory");                                    \
    if (t_ + 3 < kiters) stage(t_ + 3);                                        \
    if (t_ + 1 < kiters) {                                                     \
      const unsigned s1 = (unsigned)((t_ + 1) & 3) * 32768u;                   \
      _Pragma("unroll")                                                        \
      for (int i = 0; i < 8; ++i)                                              \
        NXT[i]     = *(const short8*)(rdA + s1 + i * 1024);                    \
      _Pragma("unroll")                                                        \
      for (int j = 0; j < 4; ++j)                                              \
        NXT[8 + j] = *(const short8*)(rdB + s1 + j * 1024);                    \
    }                                                                          \
    __builtin_amdgcn_sched_barrier(0);                                         \
    __builtin_amdgcn_s_setprio(1);                                             \
    _Pragma("unroll")                                                          \
    for (int i = 0; i < 8; ++i)                                                \
      _Pragma("unroll")                                                        \
      for (int j = 0; j < 4; ++j)                                              \
        acc[i][j] = __builtin_amdgcn_mfma_f32_16x16x32_bf16(                   \
            CUR[i], CUR[8 + j], acc[i][j], 0, 0, 0);                           \
    __builtin_amdgcn_s_setprio(0);                                             \
    __builtin_amdgcn_sched_barrier(0);                                         \
  } while (0)

  for (int t = 0; t < kiters; t += 2) {   // kiters even (32 / 64)
    TILE_BODY(t,     fA, fB);
    TILE_BODY(t + 1, fB, fA);
  }
#undef TILE_BODY

  // epilogue (no LDS use): D[row=quad*4+r][col=l16] per 16x16 tile
  #pragma unroll
  for (int i = 0; i < 8; ++i) {
    #pragma unroll
    for (int j = 0; j < 4; ++j) {
      const int row0 = bm + wm + i * 16 + quad * 4;
      const int col  = bn + wn + j * 16 + l16;
      if constexpr (MODE == 0) {
        const float bb = aux.b1[col];
        float s4[4];
        #pragma unroll
        for (int r = 0; r < 4; ++r) s4[r] = silu_f(acc[i][j][r] + bb);
        if (bn < 2048) {           // vT[b][e][t] (uniform per block)
          const int b = row0 >> 12, tt = row0 & 4095;
          ushort4 u; u.x = f2bf(s4[0]); u.y = f2bf(s4[1]); u.z = f2bf(s4[2]); u.w = f2bf(s4[3]);
          *(ushort4*)(aux.o16a + (size_t)b * 8388608 + (size_t)col * 4096 + tt) = u;
        } else {                   // gate row-major
          #pragma unroll
          for (int r = 0; r < 4; ++r)
            aux.o16b[(size_t)(row0 + r) * 2048 + (col - 2048)] = f2bf(s4[r]);
        }
      } else {  // MODE == 6
        #pragma unroll
        for (int r = 0; r < 4; ++r) {
          const size_t idx = (size_t)(row0 + r) * 1024 + col;
          aux.o32[idx] = acc[i][j][r] + aux.b1[col] + aux.x[idx];
        }
      }
    }
  }
}

// ---------------------------------------------------------------------------
// 128x128 kernel, modes 1,2,3,4.
// MODE 1: qk    M=16384 N=128  K=1024; epi silu(+b_qk): qq/lq/qkk + linkT
// MODE 2: sim   per-group M=N=256 K=128; epi /G +bias, relu^2 -> attn
// MODE 3: quad+lin per-group M=256 N=2048 K=256(attn@vT)+128(lq@linkvT); epi *gate
// MODE 4: lin_kv split-K x4 per batch M=128(d) N=2048(e) K=1024; epi fp32 pkvT
// ---------------------------------------------------------------------------
template<int MODE>
__global__ __launch_bounds__(256, 2) void gemm_k(
    const unsigned short* __restrict__ Ag,
    const unsigned short* __restrict__ Bg,
    int lda, int ldb, int kiters, Aux aux)
{
  __shared__ unsigned short As[BM * BK];
  __shared__ unsigned short Bs[BN * BK];

  const int tid  = threadIdx.x;
  const int lane = tid & 63;
  const int wave = tid >> 6;
  const int quad = lane >> 4;
  const int l16  = lane & 15;
  const int wm   = (wave >> 1) * 64;
  const int wn   = (wave & 1) * 64;
  const int bz   = blockIdx.z;
  const int bm   = blockIdx.y * BM;
  const int bn   = blockIdx.x * BN;

  const unsigned short* A = Ag;
  const unsigned short* B = Bg;
  if constexpr (MODE == 2) { A += (size_t)bz * 32768;  B += (size_t)bz * 32768; }
  if constexpr (MODE == 3) { A += (size_t)bz * 65536;                       // attn group
                             B += (size_t)(bz >> 4) * 8388608 + (size_t)(bz & 15) * 256; } // vT + g*256
  if constexpr (MODE == 4) { const int b = bz >> 2, s = bz & 3;
                             A += (size_t)b * 524288 + (size_t)s * 1024;    // linkT cols s*1024..
                             B += (size_t)b * 8388608 + (size_t)s * 1024; } // vT cols s*1024..

  const unsigned short* A2 = nullptr;
  const unsigned short* B2 = nullptr;
  if constexpr (MODE == 3) {
    A2 = aux.a2 + (size_t)bz * 32768;            // lq group (256x128)
    B2 = aux.bkv + (size_t)(bz >> 4) * 262144;   // linkvT batch (2048x128)
  }

  const int srow = wave * 32 + (lane >> 2);  // staging row (+16 for 2nd issue)
  const int scol = (lane & 3) * 8;           // staging col (8 bf16 = 16B)
  unsigned short* lA = As + wave * 1024;     // wave-uniform LDS bases
  unsigned short* lB = Bs + wave * 1024;

  const f32x4 zero = {0.f, 0.f, 0.f, 0.f};
  f32x4 acc[4][4];
  #pragma unroll
  for (int i = 0; i < 4; ++i)
    #pragma unroll
    for (int j = 0; j < 4; ++j) acc[i][j] = zero;

  for (int kt = 0; kt < kiters; ++kt) {
    const unsigned short* pa = A;
    const unsigned short* pb = B;
    int la = lda, lb = ldb, kk = kt * BK;
    if constexpr (MODE == 3) {
      if (kt >= 8) { pa = A2; pb = B2; la = 128; lb = 128; kk -= 256; }
    }

    __syncthreads();  // prior iteration's LDS reads complete
    async_cp16(pa + (size_t)(bm + srow) * la + kk + scol, lA);
    async_cp16(pa + (size_t)(bm + srow + 16) * la + kk + scol, lA + 512);
    async_cp16(pb + (size_t)(bn + srow) * lb + kk + scol, lB);
    async_cp16(pb + (size_t)(bn + srow + 16) * lb + kk + scol, lB + 512);
    __syncthreads();  // drains vmcnt (compiler) -> staged data visible

    short8 af[4], bfv[4];
    #pragma unroll
    for (int i = 0; i < 4; ++i)
      af[i] = *reinterpret_cast<const short8*>(As + (wm + i * 16 + l16) * BK + quad * 8);
    #pragma unroll
    for (int j = 0; j < 4; ++j)
      bfv[j] = *reinterpret_cast<const short8*>(Bs + (wn + j * 16 + l16) * BK + quad * 8);

    #pragma unroll
    for (int i = 0; i < 4; ++i)
      #pragma unroll
      for (int j = 0; j < 4; ++j)
        acc[i][j] = __builtin_amdgcn_mfma_f32_16x16x32_bf16(af[i], bfv[j], acc[i][j], 0, 0, 0);
  }

  // epilogue: D[row=quad*4+r][col=l16] per 16x16 tile
  #pragma unroll
  for (int i = 0; i < 4; ++i) {
    #pragma unroll
    for (int j = 0; j < 4; ++j) {
      const int row0 = bm + wm + i * 16 + quad * 4;
      const int col  = bn + wn + j * 16 + l16;
      if constexpr (MODE == 1) {
        const float bb = aux.b1[col];
        float s[4];
        #pragma unroll
        for (int r = 0; r < 4; ++r) s[r] = silu_f(acc[i][j][r] + bb);
        #pragma unroll
        for (int r = 0; r < 4; ++r) {
          const size_t idx = (size_t)(row0 + r) * 128 + col;
          aux.o16a[idx] = f2bf(s[r] * aux.gamma[col]       + aux.beta[col]);        // quad_q
          aux.o16b[idx] = f2bf(s[r] * aux.gamma[128 + col] + aux.beta[128 + col]);  // lin_q
          aux.o16c[idx] = f2bf(s[r] * aux.gamma[256 + col] + aux.beta[256 + col]);  // quad_k
        }
        const int b = row0 >> 12, t = row0 & 4095;                                  // lin_k^T
        const float g4 = aux.gamma[384 + col], b4 = aux.beta[384 + col];
        ushort4 u;
        u.x = f2bf(s[0] * g4 + b4); u.y = f2bf(s[1] * g4 + b4);
        u.z = f2bf(s[2] * g4 + b4); u.w = f2bf(s[3] * g4 + b4);
        *(ushort4*)(aux.o16d + (size_t)b * 524288 + (size_t)col * 4096 + t) = u;
      } else if constexpr (MODE == 2) {
        #pragma unroll
        for (int r = 0; r < 4; ++r) {
          float s = acc[i][j][r] * (1.0f / 256.0f) + aux.biastab[col - (row0 + r) + 255];
          s = fmaxf(s, 0.0f);
          aux.o16a[(size_t)bz * 65536 + (size_t)(row0 + r) * 256 + col] = f2bf(s * s);
        }
      } else if constexpr (MODE == 3) {
        #pragma unroll
        for (int r = 0; r < 4; ++r) {
          const size_t idx = ((size_t)bz * 256 + row0 + r) * 2048 + col;
          aux.o16a[idx] = f2bf(acc[i][j][r] * bf2f(aux.gate[idx]));
        }
      } else if constexpr (MODE == 4) {
        float4 u; u.x = acc[i][j][0]; u.y = acc[i][j][1]; u.z = acc[i][j][2]; u.w = acc[i][j][3];
        *(float4*)(aux.o32 + (size_t)bz * 262144 + (size_t)col * 128 + row0) = u;
      }
    }
  }
}

extern "C" void kernel_launch(void* const* d_in, const int* in_sizes, int n_in,
                              void* d_out, int out_size, void* d_ws, size_t ws_size,
                              hipStream_t stream) {
  (void)in_sizes; (void)n_in; (void)out_size; (void)ws_size;
  const float* x     = (const float*)d_in[0];
  const float* ln_g  = (const float*)d_in[1];
  const float* ln_b  = (const float*)d_in[2];
  const float* W_h   = (const float*)d_in[3];
  const float* b_h   = (const float*)d_in[4];
  const float* W_qk  = (const float*)d_in[5];
  const float* b_qk  = (const float*)d_in[6];
  const float* osg   = (const float*)d_in[7];
  const float* osb   = (const float*)d_in[8];
  const float* rel   = (const float*)d_in[9];
  const float* W_out = (const float*)d_in[10];
  const float* b_out = (const float*)d_in[11];
  float* out = (float*)d_out;

  // 128 KiB dynamic LDS for the 256x256 pipelined kernels (one-time).
  static bool attr_done = false;
  if (!attr_done) {
    hipFuncSetAttribute(reinterpret_cast<const void*>(gemm256_k<0>),
                        hipFuncAttributeMaxDynamicSharedMemorySize, 131072);
    hipFuncSetAttribute(reinterpret_cast<const void*>(gemm256_k<6>),
                        hipFuncAttributeMaxDynamicSharedMemorySize, 131072);
    attr_done = true;
  }

  char* w = (char*)d_ws;
  size_t off = 0;
  auto alloc = [&](size_t bytes) { char* p = w + off; off += (bytes + 255) & ~(size_t)255; return p; };

  // ---- arena R (all dead before mode 3 writes `gated`, which aliases R) ----
  unsigned short* normed = (unsigned short*)alloc(16384ull * 1024 * 2);   // 32M, dead after mode1
  unsigned short* whT    = (unsigned short*)alloc(4096ull * 1024 * 2);    //  8M, dead after mode0
  unsigned short* qq     = (unsigned short*)alloc(16384ull * 128 * 2);    //  4M, dead after mode2
  unsigned short* qkk    = (unsigned short*)alloc(16384ull * 128 * 2);    //  4M, dead after mode2
  unsigned short* linkT  = (unsigned short*)alloc(4ull * 128 * 4096 * 2); //  4M, dead after mode4
  float*          pkvT   = (float*)alloc(16ull * 2048 * 128 * 4);         // 16M, dead after kvred
  unsigned short* wqkT   = (unsigned short*)alloc(128ull * 1024 * 2);     // 256K, dead after mode1
  // ---- live-through buffers ----
  unsigned short* woutT  = (unsigned short*)alloc(1024ull * 2048 * 2);
  unsigned short* vT     = (unsigned short*)alloc(4ull * 2048 * 4096 * 2); // 64M
  unsigned short* gate   = (unsigned short*)alloc(16384ull * 2048 * 2);    // 64M
  unsigned short* lq     = (unsigned short*)alloc(16384ull * 128 * 2);
  unsigned short* attn   = (unsigned short*)alloc(64ull * 256 * 256 * 2);  //  8M
  unsigned short* linkvT = (unsigned short*)alloc(4ull * 2048 * 128 * 2);
  float*          btab   = (float*)alloc(511 * 4);
  unsigned short* gated  = (unsigned short*)w;  // alias arena R (64M needed, ~68M there)

  prep_k<<<1570, 256, 0, stream>>>(W_h, W_qk, W_out, rel, whT, wqkT, woutT, btab);
  ln_k<<<16384, 256, 0, stream>>>(x, ln_g, ln_b, normed);

  Aux a0{}; a0.b1 = b_h; a0.o16a = vT; a0.o16b = gate;
  gemm256_k<0><<<dim3(16, 64), 512, 131072, stream>>>(normed, whT, 1024, 1024, 32, a0);

  Aux a1{}; a1.b1 = b_qk; a1.gamma = osg; a1.beta = osb;
  a1.o16a = qq; a1.o16b = lq; a1.o16c = qkk; a1.o16d = linkT;
  gemm_k<1><<<dim3(1, 128, 1), 256, 0, stream>>>(normed, wqkT, 1024, 1024, 32, a1);

  Aux a2x{}; a2x.biastab = btab; a2x.o16a = attn;
  gemm_k<2><<<dim3(2, 2, 64), 256, 0, stream>>>(qq, qkk, 128, 128, 4, a2x);

  Aux a4{}; a4.o32 = pkvT;
  gemm_k<4><<<dim3(16, 1, 16), 256, 0, stream>>>(linkT, vT, 4096, 4096, 8, a4);

  kvred_k<<<1024, 256, 0, stream>>>(pkvT, linkvT);

  Aux a3{}; a3.a2 = lq; a3.bkv = linkvT; a3.gate = gate; a3.o16a = gated;
  gemm_k<3><<<dim3(16, 2, 64), 256, 0, stream>>>(attn, vT, 256, 4096, 12, a3);

  Aux a6{}; a6.b1 = b_out; a6.x = x; a6.o32 = out;
  gemm256_k<6><<<dim3(4, 64), 512, 131072, stream>>>(gated, woutT, 2048, 2048, 64, a6);
}